// Round 4
// baseline (170.869 us; speedup 1.0000x reference)
//
#include <hip/hip_runtime.h>
#include <math.h>

#define N_ROWS  32768
#define K_CODES 1024
#define D_DIM   64
#define NSPLIT  4            // K-splits (256 codes each)
#define C_SHIFT 30.0f        // logit shift keeps exp2 in fp32 range
#define LOG2E_F 1.4426950408889634f
#define LN2_F   0.6931471805599453f

// ---- ws float-index layout ----
#define WS_HIST   0                       // [1024] histogram (memset)
#define WS_ACC_H  1024                    // entropy sum (base-2 weighted)
#define WS_ACC_C  1025                    // commitment sq-diff sum
#define WS_NUSED  1026                    // used-code count
#define WS_G      2048                    // [4096] 64x64 gram partials (memset)
#define WS_E2C    6144                    // [1024] ||e||^2 + C_SHIFT (legacy order)
// per-row partials, NSPLIT splits each: [NSPLIT*N_ROWS] per array
#define PART_STRIDE (NSPLIT * N_ROWS)     // 131072
#define WS_PART_S  8192
#define WS_PART_U  (8192 + PART_STRIDE)
#define WS_PART_AB (8192 + 2 * PART_STRIDE)   // packed i1*1024+i2 (as float)
#define WS_EB      (8192 + 3 * PART_STRIDE)   // 401408
// decomposed-E records: 64 chunks x (6 frags x 64 lanes x 16B + 16 f32 e2l)
#define CHUNK_F4  388                     // float4s per chunk record
#define MAIN_CHUNKS 16                    // 16-code chunks per K-split
#define MEMSET_BYTES (6144 * 4)           // hist + accs + gram

// ---- out float-index layout (reference return order, concatenated) ----
#define OUT_Q      0
#define OUT_COMMIT 2097152
#define OUT_ORTHO  2097153
#define OUT_ENT    2097154
#define OUT_PERP   2097155
#define OUT_COV    2097156
#define OUT_IDX    2097157

typedef __attribute__((ext_vector_type(8))) short bf16x8;   // 8 bf16 = 4 VGPR
typedef __attribute__((ext_vector_type(4))) float f32x4;

// RNE fp32->bf16 (finite inputs), and exact bf16->fp32
__device__ inline unsigned short f2bf(float v) {
    unsigned int b = __float_as_uint(v);
    b += 0x7fffu + ((b >> 16) & 1u);
    return (unsigned short)(b >> 16);
}
__device__ inline float bf2f(unsigned short h) {
    return __uint_as_float(((unsigned int)h) << 16);
}
// v = hi + mid + lo (each bf16); residual subtractions are exact
__device__ inline void decomp3(float v, unsigned short &h, unsigned short &m,
                               unsigned short &l) {
    h = f2bf(v); float r1 = v - bf2f(h);
    m = f2bf(r1); float r2 = r1 - bf2f(m);
    l = f2bf(r2);
}
__device__ inline bf16x8 pack8(const unsigned short* u) {
    union { uint4 q; bf16x8 v; } cv;
    cv.q.x = (unsigned)u[0] | ((unsigned)u[1] << 16);
    cv.q.y = (unsigned)u[2] | ((unsigned)u[3] << 16);
    cv.q.z = (unsigned)u[4] | ((unsigned)u[5] << 16);
    cv.q.w = (unsigned)u[6] | ((unsigned)u[7] << 16);
    return cv.v;
}

// Bit-identical replica of the legacy fp32 logit chain (for candidate rescue)
__device__ inline float exact_g(const float4* X, const float* __restrict__ emb,
                                int k, float e2ck) {
    const float4* e4 = (const float4*)(emb + (size_t)k * D_DIM);
    float d0 = 0.f, d1 = 0.f, d2 = 0.f, d3 = 0.f;
#pragma unroll
    for (int j = 0; j < 16; j += 4) {
        float4 ea = e4[j], eb = e4[j + 1], ec = e4[j + 2], ed = e4[j + 3];
        float4 xa = X[j], xb = X[j + 1], xc = X[j + 2], xd = X[j + 3];
        d0 = fmaf(ea.x, xa.x, d0); d0 = fmaf(ea.y, xa.y, d0);
        d0 = fmaf(ea.z, xa.z, d0); d0 = fmaf(ea.w, xa.w, d0);
        d1 = fmaf(eb.x, xb.x, d1); d1 = fmaf(eb.y, xb.y, d1);
        d1 = fmaf(eb.z, xb.z, d1); d1 = fmaf(eb.w, xb.w, d1);
        d2 = fmaf(ec.x, xc.x, d2); d2 = fmaf(ec.y, xc.y, d2);
        d2 = fmaf(ec.z, xc.z, d2); d2 = fmaf(ec.w, xc.w, d2);
        d3 = fmaf(ed.x, xd.x, d3); d3 = fmaf(ed.y, xd.y, d3);
        d3 = fmaf(ed.z, xd.z, d3); d3 = fmaf(ed.w, xd.w, d3);
    }
    return fmaf(2.0f, (d0 + d1) + (d2 + d3), -e2ck);
}

// Fused prep: E-fragment decomposition (MFMA lane layout) + ||e||^2 + nused.
__global__ __launch_bounds__(256) void vq_prep(const float* __restrict__ emb,
                                               const float* __restrict__ cc,
                                               float* __restrict__ ws) {
    const int tid  = blockIdx.x * 256 + threadIdx.x;   // 0..4095
    const int c    = tid >> 6;
    const int lane = tid & 63;
    const int col  = lane & 15;
    const int kg   = lane >> 4;
    const int code = c * 16 + col;
    float4* EB4 = (float4*)(ws + WS_EB);
#pragma unroll
    for (int s = 0; s < 2; ++s) {
        const float* ep = emb + (size_t)code * D_DIM + s * 32 + kg * 8;
        float4 A4 = *(const float4*)ep;
        float4 B4 = *(const float4*)(ep + 4);
        float v[8] = {A4.x, A4.y, A4.z, A4.w, B4.x, B4.y, B4.z, B4.w};
        unsigned short H[8], M[8], L[8];
#pragma unroll
        for (int i = 0; i < 8; ++i) decomp3(v[i], H[i], M[i], L[i]);
        union { bf16x8 v8; float4 f; } th, tm, tl;
        th.v8 = pack8(H); tm.v8 = pack8(M); tl.v8 = pack8(L);
        const int base = c * CHUNK_F4 + s * 192;       // s*3*64
        EB4[base + 0 * 64 + lane] = th.f;
        EB4[base + 1 * 64 + lane] = tm.f;
        EB4[base + 2 * 64 + lane] = tl.f;
    }
    if (kg == 0) {
        // legacy sequential order -> ws[WS_E2C] bitwise matches prior rounds
        const float4* e4 = (const float4*)(emb + (size_t)code * D_DIM);
        float ssum = 0.f;
#pragma unroll
        for (int j = 0; j < 16; ++j) {
            float4 v = e4[j];
            ssum += v.x * v.x + v.y * v.y + v.z * v.z + v.w * v.w;
        }
        float e2c = ssum + C_SHIFT;
        ws[WS_E2C + code] = e2c;
        ((float*)(EB4 + c * CHUNK_F4 + 384))[col] = e2c * LOG2E_F;  // base-2
        if (cc[code] >= 1.0f) atomicAdd(&ws[WS_NUSED], 1.0f);
    }
}

#define MFMA_BF16 __builtin_amdgcn_mfma_f32_16x16x32_bf16

// 512 blocks x 256 thr. Block = (row-group of 256, K-split of 256 codes).
// Wave = 64 rows (4 tiles of 16) x 256 codes: each B-fragment load is reused
// by 4 MFMAs -> L2 traffic 203 MB total (~6 us floor).
// amdgpu_waves_per_eu(2,2): HARD max 2 waves/SIMD -> 256-reg unified budget.
// Rounds 0/1/3 proved launch_bounds min-waves does NOT stop the allocator
// from targeting 8 waves/SIMD (VGPR=44/40/56) and shuttling state through
// AGPRs (the 3x VALU inflation). This pins it.
__global__ __launch_bounds__(256)
__attribute__((amdgpu_waves_per_eu(2, 2)))
void vq_main(const float* __restrict__ inp, float* __restrict__ ws) {
    const int t    = threadIdx.x;
    const int lane = t & 63;
    const int wave = t >> 6;
    const int col  = lane & 15;
    const int kg   = lane >> 4;
    const int rg   = blockIdx.x >> 2;      // row group 0..127 (256 rows)
    const int sp   = blockIdx.x & 3;       // k split 0..3 (256 codes)
    const int wbase = rg * 256 + wave * 64;

    // ---- decompose 4 row-tiles of X into bf16x3 A-frags: xf[tile][h0,m0,l0,h1,m1,l1]
    bf16x8 xf[4][6];
#pragma unroll
    for (int tt = 0; tt < 4; ++tt) {
        const float* xp = inp + (size_t)(wbase + tt * 16 + col) * D_DIM + kg * 8;
#pragma unroll
        for (int s = 0; s < 2; ++s) {
            float4 A4 = *(const float4*)(xp + s * 32);
            float4 B4 = *(const float4*)(xp + s * 32 + 4);
            float v[8] = {A4.x, A4.y, A4.z, A4.w, B4.x, B4.y, B4.z, B4.w};
            unsigned short H[8], M[8], L[8];
#pragma unroll
            for (int i = 0; i < 8; ++i) decomp3(v[i], H[i], M[i], L[i]);
            xf[tt][s * 3 + 0] = pack8(H);
            xf[tt][s * 3 + 1] = pack8(M);
            xf[tt][s * 3 + 2] = pack8(L);
        }
    }

    const float4* EBp = (const float4*)(ws + WS_EB)
                      + (size_t)sp * MAIN_CHUNKS * CHUNK_F4;

    float sa[4][4], ua[4][4], m1[4][4], m2[4][4];
    int i1[4][4], i2[4][4];
#pragma unroll
    for (int tt = 0; tt < 4; ++tt)
#pragma unroll
        for (int q = 0; q < 4; ++q) {
            sa[tt][q] = 0.f; ua[tt][q] = 0.f;
            m1[tt][q] = -1e30f; m2[tt][q] = -1e30f;
            i1[tt][q] = 0; i2[tt][q] = 0;
        }

#pragma unroll 2
    for (int c = 0; c < MAIN_CHUNKS; ++c) {
        const float4* p = EBp + (size_t)c * CHUNK_F4;
        const bf16x8* pb = (const bf16x8*)p;
        bf16x8 b0 = pb[0 * 64 + lane];     // h, k-step 0
        bf16x8 b1 = pb[1 * 64 + lane];     // m
        bf16x8 b2 = pb[2 * 64 + lane];     // l
        bf16x8 b3 = pb[3 * 64 + lane];     // h, k-step 1
        bf16x8 b4 = pb[4 * 64 + lane];     // m
        bf16x8 b5 = pb[5 * 64 + lane];     // l
        const float e2v = ((const float*)(p + 384))[col];

        f32x4 acc[4];
#pragma unroll
        for (int tt = 0; tt < 4; ++tt) acc[tt] = (f32x4){0.f, 0.f, 0.f, 0.f};

        // 6-term bf16x3 per k-step; tile-inner loops keep 4 chains independent
#pragma unroll
        for (int tt = 0; tt < 4; ++tt) acc[tt] = MFMA_BF16(xf[tt][0], b0, acc[tt], 0, 0, 0);
#pragma unroll
        for (int tt = 0; tt < 4; ++tt) acc[tt] = MFMA_BF16(xf[tt][0], b1, acc[tt], 0, 0, 0);
#pragma unroll
        for (int tt = 0; tt < 4; ++tt) acc[tt] = MFMA_BF16(xf[tt][1], b0, acc[tt], 0, 0, 0);
#pragma unroll
        for (int tt = 0; tt < 4; ++tt) acc[tt] = MFMA_BF16(xf[tt][0], b2, acc[tt], 0, 0, 0);
#pragma unroll
        for (int tt = 0; tt < 4; ++tt) acc[tt] = MFMA_BF16(xf[tt][2], b0, acc[tt], 0, 0, 0);
#pragma unroll
        for (int tt = 0; tt < 4; ++tt) acc[tt] = MFMA_BF16(xf[tt][1], b1, acc[tt], 0, 0, 0);
#pragma unroll
        for (int tt = 0; tt < 4; ++tt) acc[tt] = MFMA_BF16(xf[tt][3], b3, acc[tt], 0, 0, 0);
#pragma unroll
        for (int tt = 0; tt < 4; ++tt) acc[tt] = MFMA_BF16(xf[tt][3], b4, acc[tt], 0, 0, 0);
#pragma unroll
        for (int tt = 0; tt < 4; ++tt) acc[tt] = MFMA_BF16(xf[tt][4], b3, acc[tt], 0, 0, 0);
#pragma unroll
        for (int tt = 0; tt < 4; ++tt) acc[tt] = MFMA_BF16(xf[tt][3], b5, acc[tt], 0, 0, 0);
#pragma unroll
        for (int tt = 0; tt < 4; ++tt) acc[tt] = MFMA_BF16(xf[tt][5], b3, acc[tt], 0, 0, 0);
#pragma unroll
        for (int tt = 0; tt < 4; ++tt) acc[tt] = MFMA_BF16(xf[tt][4], b4, acc[tt], 0, 0, 0);

        const int cb = sp * 256 + c * 16 + col;        // global code index
#pragma unroll
        for (int tt = 0; tt < 4; ++tt)
#pragma unroll
            for (int q = 0; q < 4; ++q) {
                // base-2 shifted logit: g = 2*log2e*dot - log2e*(e2+C_SHIFT)
                float g = fmaf(2.0f * LOG2E_F, acc[tt][q], -e2v);
                float pw;
                asm("v_exp_f32 %0, %1" : "=v"(pw) : "v"(g));   // 2^g
                sa[tt][q] += pw;
                ua[tt][q] = fmaf(pw, g, ua[tt][q]);
                bool gt1 = g > m1[tt][q];
                bool gt2 = g > m2[tt][q];
                i2[tt][q] = gt1 ? i1[tt][q] : (gt2 ? cb : i2[tt][q]);
                m2[tt][q] = fminf(fmaxf(g, m2[tt][q]), m1[tt][q]); // med3
                i1[tt][q] = gt1 ? cb : i1[tt][q];
                m1[tt][q] = fmaxf(m1[tt][q], g);
            }
    }

    // per-row reduce across the 16 lanes sharing each C-row
#pragma unroll
    for (int off = 1; off < 16; off <<= 1) {
#pragma unroll
        for (int tt = 0; tt < 4; ++tt)
#pragma unroll
            for (int q = 0; q < 4; ++q) {
                sa[tt][q] += __shfl_xor(sa[tt][q], off);
                ua[tt][q] += __shfl_xor(ua[tt][q], off);
                float bm1 = __shfl_xor(m1[tt][q], off);
                int   bi1 = __shfl_xor(i1[tt][q], off);
                float bm2 = __shfl_xor(m2[tt][q], off);
                int   bi2 = __shfl_xor(i2[tt][q], off);
                if (bm1 > m1[tt][q]) {
                    m2[tt][q] = m1[tt][q]; i2[tt][q] = i1[tt][q];
                    m1[tt][q] = bm1;       i1[tt][q] = bi1;
                    if (bm2 > m2[tt][q]) { m2[tt][q] = bm2; i2[tt][q] = bi2; }
                } else if (bm1 > m2[tt][q]) {
                    m2[tt][q] = bm1; i2[tt][q] = bi1;
                }
            }
    }

    if (col == 0) {
#pragma unroll
        for (int tt = 0; tt < 4; ++tt)
#pragma unroll
            for (int q = 0; q < 4; ++q) {
                const int r  = wbase + tt * 16 + kg * 4 + q;
                const int pi = sp * N_ROWS + r;
                ws[WS_PART_S + pi]  = sa[tt][q];
                ws[WS_PART_U + pi]  = ua[tt][q];
                ws[WS_PART_AB + pi] = (float)(i1[tt][q] * 1024 + i2[tt][q]);
            }
    }
}

// 512 blocks x 64 thr (full-GPU spread); thread = row. Merge 4 splits, exact
// fp32 rescue of the <=8 approx candidates (legacy argmin semantics), epilogue.
__global__ __launch_bounds__(64) void vq_combine(const float* __restrict__ inp,
                                                 const float* __restrict__ emb,
                                                 float* __restrict__ ws,
                                                 float* __restrict__ out) {
    const int lane = threadIdx.x;
    const int row  = blockIdx.x * 64 + lane;

    float S = 0.f, U2 = 0.f;
    int cand[8];
#pragma unroll
    for (int sp = 0; sp < NSPLIT; ++sp) {
        const int pi = sp * N_ROWS + row;
        S  += ws[WS_PART_S + pi];
        U2 += ws[WS_PART_U + pi];
        int ab = (int)ws[WS_PART_AB + pi];
        cand[2 * sp]     = ab >> 10;
        cand[2 * sp + 1] = ab & 1023;
    }
    float U = U2 * LN2_F;                             // base-2 -> nats

    float4 X[16];
    const float4* xr = (const float4*)(inp + (size_t)row * D_DIM);
#pragma unroll
    for (int j = 0; j < 16; ++j) X[j] = xr[j];

    float bestg = -1e30f; int I = K_CODES;
#pragma unroll 2
    for (int j = 0; j < 8; ++j) {
        const int c = cand[j];
        float g = exact_g(X, emb, c, ws[WS_E2C + c]);
        if (g > bestg || (g == bestg && c < I)) { bestg = g; I = c; }
    }

    float H = logf(S) - U / S;                        // per-row entropy (nats)

    out[OUT_IDX + row] = (float)I;
    atomicAdd(&ws[WS_HIST + I], 1.0f);

    const float4* q4 = (const float4*)(emb + (size_t)I * D_DIM);
    float4* oq = (float4*)out + (size_t)row * 16;
    float cs = 0.f;
#pragma unroll
    for (int j = 0; j < 16; ++j) {
        float4 q = q4[j], x = X[j];
        float dx = q.x - x.x, dy = q.y - x.y, dz = q.z - x.z, dw = q.w - x.w;
        cs += dx * dx + dy * dy + dz * dz + dw * dw;
        float4 o;
        o.x = x.x + dx; o.y = x.y + dy; o.z = x.z + dz; o.w = x.w + dw;
        oq[j] = o;
    }
#pragma unroll
    for (int off = 32; off; off >>= 1) {
        H  += __shfl_down(H, off);
        cs += __shfl_down(cs, off);
    }
    if (lane == 0) {
        atomicAdd(&ws[WS_ACC_H], H);
        atomicAdd(&ws[WS_ACC_C], cs);
    }
}

// 16 blocks x 256 threads; block b owns codes [64b, 64b+64). Partial 64x64
// Gram of masked-normalized rows, atomicAdd into ws[WS_G].
__global__ __launch_bounds__(256) void vq_ortho_part(const float* __restrict__ emb,
                                                     const float* __restrict__ cc,
                                                     float* __restrict__ ws) {
    __shared__ float srows[64][64];
    __shared__ float rn2[64];

    const int t  = threadIdx.x;
    const int k0 = blockIdx.x * 64;
    const int rb = t >> 4;            // 0..15
    const int c4 = (t & 15) << 2;     // float4 col

#pragma unroll
    for (int i = 0; i < 4; ++i) {
        const int r = i * 16 + rb;
        float4 v = *(const float4*)(emb + (size_t)(k0 + r) * D_DIM + c4);
        *(float4*)(&srows[r][c4]) = v;
        float ss = v.x * v.x + v.y * v.y + v.z * v.z + v.w * v.w;
        ss += __shfl_down(ss, 8, 16);
        ss += __shfl_down(ss, 4, 16);
        ss += __shfl_down(ss, 2, 16);
        ss += __shfl_down(ss, 1, 16);
        if ((t & 15) == 0) {
            float nrm = fmaxf(sqrtf(ss), 1e-12f);
            float m = (cc[k0 + r] >= 1.0f) ? 1.0f : 0.0f;
            rn2[r] = m / (nrm * nrm);     // rnorm^2, folded into A side
        }
    }
    __syncthreads();

    const int a  = t >> 2;
    const int b0 = (t & 3) << 4;
    float acc[16];
#pragma unroll
    for (int i = 0; i < 16; ++i) acc[i] = 0.f;

#pragma unroll 4
    for (int k = 0; k < 64; ++k) {
        float na = srows[k][a] * rn2[k];
        const float* rbp = &srows[k][b0];
#pragma unroll
        for (int i = 0; i < 16; ++i) acc[i] = fmaf(na, rbp[i], acc[i]);
    }
#pragma unroll
    for (int i = 0; i < 16; ++i)
        atomicAdd(&ws[WS_G + a * 64 + b0 + i], acc[i]);
}

__global__ __launch_bounds__(256) void vq_finalize(const float* __restrict__ ws,
                                                   float* __restrict__ out) {
    __shared__ float redP[4], redG[4];
    const int t = threadIdx.x;
    float hp = 0.f, gg = 0.f;
    for (int k = t; k < K_CODES; k += 256) {
        float p = ws[WS_HIST + k] * (1.0f / (float)N_ROWS);
        hp += p * logf(p + 1e-10f);
    }
    for (int i = t; i < 4096; i += 256) {
        float g = ws[WS_G + i];
        gg = fmaf(g, g, gg);
    }
#pragma unroll
    for (int off = 32; off; off >>= 1) {
        hp += __shfl_down(hp, off);
        gg += __shfl_down(gg, off);
    }
    if ((t & 63) == 0) { redP[t >> 6] = hp; redG[t >> 6] = gg; }
    __syncthreads();
    if (t == 0) {
        float hsum = redP[0] + redP[1] + redP[2] + redP[3];
        float gsum = redG[0] + redG[1] + redG[2] + redG[3];
        float nu = ws[WS_NUSED];
        out[OUT_PERP]   = expf(-hsum);
        out[OUT_ENT]    = ws[WS_ACC_H] * (1.0f / (float)N_ROWS) * 0.1f; // /log2(1024)
        out[OUT_COMMIT] = ws[WS_ACC_C] * (1.0f / ((float)N_ROWS * (float)D_DIM));
        out[OUT_ORTHO]  = gsum / (nu * nu) - 1.0f / nu;
        out[OUT_COV]    = nu * (1.0f / (float)K_CODES);
    }
}

extern "C" void kernel_launch(void* const* d_in, const int* in_sizes, int n_in,
                              void* d_out, int out_size, void* d_ws, size_t ws_size,
                              hipStream_t stream) {
    const float* inp = (const float*)d_in[0];   // [16,2048,64]
    const float* emb = (const float*)d_in[1];   // [1024,64]
    const float* cc  = (const float*)d_in[2];   // [1024]
    float* out = (float*)d_out;
    float* ws  = (float*)d_ws;

    hipMemsetAsync(d_ws, 0, MEMSET_BYTES, stream);
    vq_prep<<<16, 256, 0, stream>>>(emb, cc, ws);
    vq_main<<<(N_ROWS / 256) * NSPLIT, 256, 0, stream>>>(inp, ws);
    vq_combine<<<N_ROWS / 64, 64, 0, stream>>>(inp, emb, ws, out);
    vq_ortho_part<<<16, 256, 0, stream>>>(emb, cc, ws);
    vq_finalize<<<1, 256, 0, stream>>>(ws, out);
}

// Round 5
// 153.324 us; speedup vs baseline: 1.1144x; 1.1144x over previous
//
#include <hip/hip_runtime.h>
#include <math.h>

#define N_ROWS  32768
#define K_CODES 1024
#define D_DIM   64
#define NSPLIT  2            // K-splits (512 codes each)
#define C_SHIFT 30.0f        // logit shift keeps exp2 in fp32 range
#define LOG2E_F 1.4426950408889634f
#define LN2_F   0.6931471805599453f

// ---- ws float-index layout ----
#define WS_HIST   0                       // [1024] histogram (memset)
#define WS_ACC_H  1024                    // entropy sum (base-2 weighted)
#define WS_ACC_C  1025                    // commitment sq-diff sum
#define WS_NUSED  1026                    // used-code count
#define WS_G      2048                    // [4096] 64x64 gram partials (memset)
#define WS_E2C    6144                    // [1024] ||e||^2 + C_SHIFT (legacy order)
// per-row partials, NSPLIT splits each
#define PART_STRIDE (NSPLIT * N_ROWS)     // 65536
#define WS_PART_S  8192
#define WS_PART_U  (8192 + PART_STRIDE)
#define WS_PART_AB (8192 + 2 * PART_STRIDE)   // packed i1*1024+i2 (as float)
#define WS_EB      (8192 + 3 * PART_STRIDE)   // 204800
// fp16x2 E records: 64 chunks x (4 frags x 64 lanes x 16B + 16 f32 e2l)
#define CHUNK_F4  260                     // float4s per chunk record
#define MAIN_CHUNKS 32                    // 16-code chunks per K-split
#define MEMSET_BYTES (6144 * 4)           // hist + accs + gram

// ---- out float-index layout (reference return order, concatenated) ----
#define OUT_Q      0
#define OUT_COMMIT 2097152
#define OUT_ORTHO  2097153
#define OUT_ENT    2097154
#define OUT_PERP   2097155
#define OUT_COV    2097156
#define OUT_IDX    2097157

typedef __attribute__((ext_vector_type(8))) _Float16 f16x8;  // 8 f16 = 4 VGPR
typedef __attribute__((ext_vector_type(4))) float f32x4;

// Bit-identical replica of the legacy fp32 logit chain (for candidate rescue)
__device__ inline float exact_g(const float4* X, const float* __restrict__ emb,
                                int k, float e2ck) {
    const float4* e4 = (const float4*)(emb + (size_t)k * D_DIM);
    float d0 = 0.f, d1 = 0.f, d2 = 0.f, d3 = 0.f;
#pragma unroll
    for (int j = 0; j < 16; j += 4) {
        float4 ea = e4[j], eb = e4[j + 1], ec = e4[j + 2], ed = e4[j + 3];
        float4 xa = X[j], xb = X[j + 1], xc = X[j + 2], xd = X[j + 3];
        d0 = fmaf(ea.x, xa.x, d0); d0 = fmaf(ea.y, xa.y, d0);
        d0 = fmaf(ea.z, xa.z, d0); d0 = fmaf(ea.w, xa.w, d0);
        d1 = fmaf(eb.x, xb.x, d1); d1 = fmaf(eb.y, xb.y, d1);
        d1 = fmaf(eb.z, xb.z, d1); d1 = fmaf(eb.w, xb.w, d1);
        d2 = fmaf(ec.x, xc.x, d2); d2 = fmaf(ec.y, xc.y, d2);
        d2 = fmaf(ec.z, xc.z, d2); d2 = fmaf(ec.w, xc.w, d2);
        d3 = fmaf(ed.x, xd.x, d3); d3 = fmaf(ed.y, xd.y, d3);
        d3 = fmaf(ed.z, xd.z, d3); d3 = fmaf(ed.w, xd.w, d3);
    }
    return fmaf(2.0f, (d0 + d1) + (d2 + d3), -e2ck);
}

// fp16x2 decomposition of 8 floats -> (hi, mid) f16x8 pair.
// x = h + m + r with |r| <= 2^-23|x| -> (xh+xm)(eh+em) reproduces the fp32
// dot to ~1e-6 abs (== the fp32-MFMA-accumulation noise floor), in 4 terms.
__device__ inline void decomp2x8(const float* v, f16x8& h, f16x8& m) {
#pragma unroll
    for (int i = 0; i < 8; ++i) {
        _Float16 hh = (_Float16)v[i];
        h[i] = hh;
        m[i] = (_Float16)(v[i] - (float)hh);
    }
}

// Fused prep: E-fragment fp16x2 decomposition (MFMA lane layout) + ||e||^2.
// 16 blocks x 256; tid -> (chunk c = tid>>6, lane). col=lane&15 (code),
// kg=lane>>4 selects k-elems kg*8 within each 32-wide k-step.
__global__ __launch_bounds__(256) void vq_prep(const float* __restrict__ emb,
                                               const float* __restrict__ cc,
                                               float* __restrict__ ws) {
    const int tid  = blockIdx.x * 256 + threadIdx.x;   // 0..4095
    const int c    = tid >> 6;
    const int lane = tid & 63;
    const int col  = lane & 15;
    const int kg   = lane >> 4;
    const int code = c * 16 + col;
    float4* EB4 = (float4*)(ws + WS_EB);
#pragma unroll
    for (int s = 0; s < 2; ++s) {
        const float* ep = emb + (size_t)code * D_DIM + s * 32 + kg * 8;
        float4 A4 = *(const float4*)ep;
        float4 B4 = *(const float4*)(ep + 4);
        float v[8] = {A4.x, A4.y, A4.z, A4.w, B4.x, B4.y, B4.z, B4.w};
        union { f16x8 h; float4 f; } th, tm;
        decomp2x8(v, th.h, tm.h);
        const int base = c * CHUNK_F4;
        EB4[base + (s * 2 + 0) * 64 + lane] = th.f;   // hi  frag, k-step s
        EB4[base + (s * 2 + 1) * 64 + lane] = tm.f;   // mid frag, k-step s
    }
    if (kg == 0) {
        // legacy sequential order -> ws[WS_E2C] bitwise matches prior rounds
        const float4* e4 = (const float4*)(emb + (size_t)code * D_DIM);
        float ssum = 0.f;
#pragma unroll
        for (int j = 0; j < 16; ++j) {
            float4 v = e4[j];
            ssum += v.x * v.x + v.y * v.y + v.z * v.z + v.w * v.w;
        }
        float e2c = ssum + C_SHIFT;
        ws[WS_E2C + code] = e2c;
        ((float*)(EB4 + c * CHUNK_F4 + 256))[col] = e2c * LOG2E_F;  // base-2
        if (cc[code] >= 1.0f) atomicAdd(&ws[WS_NUSED], 1.0f);
    }
}

#define MFMA_F16 __builtin_amdgcn_mfma_f32_16x16x32_f16

// 512 blocks x 256 thr. Block = (row-group of 128, K-split of 512 codes).
// Wave = 32 rows (2 tiles of 16) x 512 codes; fp16x2 4-term MFMA emulation.
// Register budget is THE design constraint (rounds 0/1/3/4 evidence):
// demand ~115 arch VGPRs fits the 128-reg tier; waves_per_eu(4,4) pins the
// allocator there (min alone is ignored: it targeted 8 waves at VGPR=56;
// (2,2) with demand 245 spilled 11MB to scratch). No LDS, no barriers:
// fragment table is L2/L1-resident; block's 4 waves walk the same chunks
// in loose lockstep -> L1 reuse.
__global__ __launch_bounds__(256)
__attribute__((amdgpu_waves_per_eu(4, 4)))
void vq_main(const float* __restrict__ inp, float* __restrict__ ws) {
    const int t    = threadIdx.x;
    const int lane = t & 63;
    const int wave = t >> 6;
    const int col  = lane & 15;
    const int kg   = lane >> 4;
    const int rg   = blockIdx.x >> 1;      // row group 0..255 (128 rows)
    const int sp   = blockIdx.x & 1;       // k split 0..1 (512 codes)
    const int wbase = rg * 128 + wave * 32;

    // A-frags: xa[tile][0]=h k0, [1]=m k0, [2]=h k1, [3]=m k1
    f16x8 xa[2][4];
#pragma unroll
    for (int tt = 0; tt < 2; ++tt) {
        const float* xp = inp + (size_t)(wbase + tt * 16 + col) * D_DIM + kg * 8;
#pragma unroll
        for (int s = 0; s < 2; ++s) {
            float4 A4 = *(const float4*)(xp + s * 32);
            float4 B4 = *(const float4*)(xp + s * 32 + 4);
            float v[8] = {A4.x, A4.y, A4.z, A4.w, B4.x, B4.y, B4.z, B4.w};
            decomp2x8(v, xa[tt][s * 2 + 0], xa[tt][s * 2 + 1]);
        }
    }

    const float4* EBp = (const float4*)(ws + WS_EB)
                      + (size_t)sp * MAIN_CHUNKS * CHUNK_F4;

    float sa[2][4], ua[2][4], m1[2][4], m2[2][4];
    int i12[2][4];
#pragma unroll
    for (int tt = 0; tt < 2; ++tt)
#pragma unroll
        for (int q = 0; q < 4; ++q) {
            sa[tt][q] = 0.f; ua[tt][q] = 0.f;
            m1[tt][q] = -1e30f; m2[tt][q] = -1e30f;
            i12[tt][q] = 0;
        }

#pragma unroll 2
    for (int c = 0; c < MAIN_CHUNKS; ++c) {
        const float4* p = EBp + (size_t)c * CHUNK_F4;
        const f16x8* pb = (const f16x8*)p;
        f16x8 bh0 = pb[0 * 64 + lane];     // hi,  k-step 0
        f16x8 bm0 = pb[1 * 64 + lane];     // mid, k-step 0
        f16x8 bh1 = pb[2 * 64 + lane];     // hi,  k-step 1
        f16x8 bm1 = pb[3 * 64 + lane];     // mid, k-step 1
        const float e2v = ((const float*)(p + 256))[col];

        f32x4 acc[2];
#pragma unroll
        for (int tt = 0; tt < 2; ++tt) acc[tt] = (f32x4){0.f, 0.f, 0.f, 0.f};

        // 4-term fp16x2 per k-step; tile-interleave keeps 2 chains independent
#pragma unroll
        for (int tt = 0; tt < 2; ++tt) acc[tt] = MFMA_F16(xa[tt][0], bh0, acc[tt], 0, 0, 0);
#pragma unroll
        for (int tt = 0; tt < 2; ++tt) acc[tt] = MFMA_F16(xa[tt][2], bh1, acc[tt], 0, 0, 0);
#pragma unroll
        for (int tt = 0; tt < 2; ++tt) acc[tt] = MFMA_F16(xa[tt][1], bh0, acc[tt], 0, 0, 0);
#pragma unroll
        for (int tt = 0; tt < 2; ++tt) acc[tt] = MFMA_F16(xa[tt][3], bh1, acc[tt], 0, 0, 0);
#pragma unroll
        for (int tt = 0; tt < 2; ++tt) acc[tt] = MFMA_F16(xa[tt][0], bm0, acc[tt], 0, 0, 0);
#pragma unroll
        for (int tt = 0; tt < 2; ++tt) acc[tt] = MFMA_F16(xa[tt][2], bm1, acc[tt], 0, 0, 0);
#pragma unroll
        for (int tt = 0; tt < 2; ++tt) acc[tt] = MFMA_F16(xa[tt][1], bm0, acc[tt], 0, 0, 0);
#pragma unroll
        for (int tt = 0; tt < 2; ++tt) acc[tt] = MFMA_F16(xa[tt][3], bm1, acc[tt], 0, 0, 0);

        const int cb = sp * 512 + c * 16 + col;        // global code index
#pragma unroll
        for (int tt = 0; tt < 2; ++tt)
#pragma unroll
            for (int q = 0; q < 4; ++q) {
                // base-2 shifted logit: g = 2*log2e*dot - log2e*(e2+C_SHIFT)
                float g = fmaf(2.0f * LOG2E_F, acc[tt][q], -e2v);
                float pw;
                asm("v_exp_f32 %0, %1" : "=v"(pw) : "v"(g));   // 2^g
                sa[tt][q] += pw;
                ua[tt][q] = fmaf(pw, g, ua[tt][q]);
                bool gt1 = g > m1[tt][q];
                bool gt2 = g > m2[tt][q];
                int t1 = (cb << 10) | (i12[tt][q] >> 10);      // new i1=cb, i2=old i1
                int t2 = (i12[tt][q] & ~1023) | cb;            // new i2=cb
                i12[tt][q] = gt1 ? t1 : (gt2 ? t2 : i12[tt][q]);
                m2[tt][q] = fminf(fmaxf(g, m2[tt][q]), m1[tt][q]);  // med3
                m1[tt][q] = fmaxf(m1[tt][q], g);
            }
    }

    // per-row reduce across the 16 lanes sharing each C-row
#pragma unroll
    for (int off = 1; off < 16; off <<= 1) {
#pragma unroll
        for (int tt = 0; tt < 2; ++tt)
#pragma unroll
            for (int q = 0; q < 4; ++q) {
                sa[tt][q] += __shfl_xor(sa[tt][q], off);
                ua[tt][q] += __shfl_xor(ua[tt][q], off);
                float bm1v = __shfl_xor(m1[tt][q], off);
                float bm2v = __shfl_xor(m2[tt][q], off);
                int   biv  = __shfl_xor(i12[tt][q], off);
                if (bm1v > m1[tt][q]) {
                    if (bm2v > m1[tt][q]) {        // both from partner
                        m2[tt][q] = bm2v; i12[tt][q] = biv;
                    } else {                        // partner's 1st, our 1st
                        m2[tt][q] = m1[tt][q];
                        i12[tt][q] = (biv & ~1023 & 0xFFFFFC00) | (i12[tt][q] >> 10);
                        i12[tt][q] = ((biv >> 10) << 10) | (i12[tt][q] & 1023);
                    }
                    m1[tt][q] = bm1v;
                } else if (bm1v > m2[tt][q]) {      // partner's 1st is our 2nd
                    m2[tt][q] = bm1v;
                    i12[tt][q] = (i12[tt][q] & ~1023) | (biv >> 10);
                }
            }
    }

    if (col == 0) {
#pragma unroll
        for (int tt = 0; tt < 2; ++tt)
#pragma unroll
            for (int q = 0; q < 4; ++q) {
                const int r  = wbase + tt * 16 + kg * 4 + q;
                const int pi = sp * N_ROWS + r;
                ws[WS_PART_S + pi]  = sa[tt][q];
                ws[WS_PART_U + pi]  = ua[tt][q];
                ws[WS_PART_AB + pi] = (float)i12[tt][q];
            }
    }
}

// 512 blocks x 64 thr; thread = row. Merge 2 splits, exact fp32 rescue of the
// <=4 approx candidates (legacy argmin semantics), epilogue.
__global__ __launch_bounds__(64) void vq_combine(const float* __restrict__ inp,
                                                 const float* __restrict__ emb,
                                                 float* __restrict__ ws,
                                                 float* __restrict__ out) {
    const int lane = threadIdx.x;
    const int row  = blockIdx.x * 64 + lane;

    float S = 0.f, U2 = 0.f;
    int cand[4];
#pragma unroll
    for (int sp = 0; sp < NSPLIT; ++sp) {
        const int pi = sp * N_ROWS + row;
        S  += ws[WS_PART_S + pi];
        U2 += ws[WS_PART_U + pi];
        int ab = (int)ws[WS_PART_AB + pi];
        cand[2 * sp]     = ab >> 10;
        cand[2 * sp + 1] = ab & 1023;
    }
    float U = U2 * LN2_F;                             // base-2 -> nats

    float4 X[16];
    const float4* xr = (const float4*)(inp + (size_t)row * D_DIM);
#pragma unroll
    for (int j = 0; j < 16; ++j) X[j] = xr[j];

    float bestg = -1e30f; int I = K_CODES;
#pragma unroll
    for (int j = 0; j < 4; ++j) {
        const int c = cand[j];
        float g = exact_g(X, emb, c, ws[WS_E2C + c]);
        if (g > bestg || (g == bestg && c < I)) { bestg = g; I = c; }
    }

    float H = logf(S) - U / S;                        // per-row entropy (nats)

    out[OUT_IDX + row] = (float)I;
    atomicAdd(&ws[WS_HIST + I], 1.0f);

    const float4* q4 = (const float4*)(emb + (size_t)I * D_DIM);
    float4* oq = (float4*)out + (size_t)row * 16;
    float cs = 0.f;
#pragma unroll
    for (int j = 0; j < 16; ++j) {
        float4 q = q4[j], x = X[j];
        float dx = q.x - x.x, dy = q.y - x.y, dz = q.z - x.z, dw = q.w - x.w;
        cs += dx * dx + dy * dy + dz * dz + dw * dw;
        float4 o;
        o.x = x.x + dx; o.y = x.y + dy; o.z = x.z + dz; o.w = x.w + dw;
        oq[j] = o;
    }
#pragma unroll
    for (int off = 32; off; off >>= 1) {
        H  += __shfl_down(H, off);
        cs += __shfl_down(cs, off);
    }
    if (lane == 0) {
        atomicAdd(&ws[WS_ACC_H], H);
        atomicAdd(&ws[WS_ACC_C], cs);
    }
}

// 16 blocks x 256 threads; block b owns codes [64b, 64b+64). Partial 64x64
// Gram of masked-normalized rows, atomicAdd into ws[WS_G].
__global__ __launch_bounds__(256) void vq_ortho_part(const float* __restrict__ emb,
                                                     const float* __restrict__ cc,
                                                     float* __restrict__ ws) {
    __shared__ float srows[64][64];
    __shared__ float rn2[64];

    const int t  = threadIdx.x;
    const int k0 = blockIdx.x * 64;
    const int rb = t >> 4;            // 0..15
    const int c4 = (t & 15) << 2;     // float4 col

#pragma unroll
    for (int i = 0; i < 4; ++i) {
        const int r = i * 16 + rb;
        float4 v = *(const float4*)(emb + (size_t)(k0 + r) * D_DIM + c4);
        *(float4*)(&srows[r][c4]) = v;
        float ss = v.x * v.x + v.y * v.y + v.z * v.z + v.w * v.w;
        ss += __shfl_down(ss, 8, 16);
        ss += __shfl_down(ss, 4, 16);
        ss += __shfl_down(ss, 2, 16);
        ss += __shfl_down(ss, 1, 16);
        if ((t & 15) == 0) {
            float nrm = fmaxf(sqrtf(ss), 1e-12f);
            float m = (cc[k0 + r] >= 1.0f) ? 1.0f : 0.0f;
            rn2[r] = m / (nrm * nrm);     // rnorm^2, folded into A side
        }
    }
    __syncthreads();

    const int a  = t >> 2;
    const int b0 = (t & 3) << 4;
    float acc[16];
#pragma unroll
    for (int i = 0; i < 16; ++i) acc[i] = 0.f;

#pragma unroll 4
    for (int k = 0; k < 64; ++k) {
        float na = srows[k][a] * rn2[k];
        const float* rbp = &srows[k][b0];
#pragma unroll
        for (int i = 0; i < 16; ++i) acc[i] = fmaf(na, rbp[i], acc[i]);
    }
#pragma unroll
    for (int i = 0; i < 16; ++i)
        atomicAdd(&ws[WS_G + a * 64 + b0 + i], acc[i]);
}

__global__ __launch_bounds__(256) void vq_finalize(const float* __restrict__ ws,
                                                   float* __restrict__ out) {
    __shared__ float redP[4], redG[4];
    const int t = threadIdx.x;
    float hp = 0.f, gg = 0.f;
    for (int k = t; k < K_CODES; k += 256) {
        float p = ws[WS_HIST + k] * (1.0f / (float)N_ROWS);
        hp += p * logf(p + 1e-10f);
    }
    for (int i = t; i < 4096; i += 256) {
        float g = ws[WS_G + i];
        gg = fmaf(g, g, gg);
    }
#pragma unroll
    for (int off = 32; off; off >>= 1) {
        hp += __shfl_down(hp, off);
        gg += __shfl_down(gg, off);
    }
    if ((t & 63) == 0) { redP[t >> 6] = hp; redG[t >> 6] = gg; }
    __syncthreads();
    if (t == 0) {
        float hsum = redP[0] + redP[1] + redP[2] + redP[3];
        float gsum = redG[0] + redG[1] + redG[2] + redG[3];
        float nu = ws[WS_NUSED];
        out[OUT_PERP]   = expf(-hsum);
        out[OUT_ENT]    = ws[WS_ACC_H] * (1.0f / (float)N_ROWS) * 0.1f; // /log2(1024)
        out[OUT_COMMIT] = ws[WS_ACC_C] * (1.0f / ((float)N_ROWS * (float)D_DIM));
        out[OUT_ORTHO]  = gsum / (nu * nu) - 1.0f / nu;
        out[OUT_COV]    = nu * (1.0f / (float)K_CODES);
    }
}

extern "C" void kernel_launch(void* const* d_in, const int* in_sizes, int n_in,
                              void* d_out, int out_size, void* d_ws, size_t ws_size,
                              hipStream_t stream) {
    const float* inp = (const float*)d_in[0];   // [16,2048,64]
    const float* emb = (const float*)d_in[1];   // [1024,64]
    const float* cc  = (const float*)d_in[2];   // [1024]
    float* out = (float*)d_out;
    float* ws  = (float*)d_ws;

    hipMemsetAsync(d_ws, 0, MEMSET_BYTES, stream);
    vq_prep<<<16, 256, 0, stream>>>(emb, cc, ws);
    vq_main<<<(N_ROWS / 128) * NSPLIT, 256, 0, stream>>>(inp, ws);
    vq_combine<<<N_ROWS / 64, 64, 0, stream>>>(inp, emb, ws, out);
    vq_ortho_part<<<16, 256, 0, stream>>>(emb, cc, ws);
    vq_finalize<<<1, 256, 0, stream>>>(ws, out);
}

// Round 6
// 148.320 us; speedup vs baseline: 1.1520x; 1.0337x over previous
//
#include <hip/hip_runtime.h>
#include <math.h>

#define N_ROWS  32768
#define K_CODES 1024
#define D_DIM   64
#define NSPLIT  4            // K-splits (256 codes each)
#define C_SHIFT 30.0f        // logit shift keeps exp2 in fp32 range
#define LOG2E_F 1.4426950408889634f
#define LN2_F   0.6931471805599453f

// ---- ws float-index layout ----
#define WS_HIST   0                       // [1024] histogram (memset)
#define WS_ACC_H  1024                    // entropy sum (base-2 weighted)
#define WS_ACC_C  1025                    // commitment sq-diff sum
#define WS_NUSED  1026                    // used-code count
#define WS_G      2048                    // [4096] 64x64 gram partials (memset)
#define WS_E2C    6144                    // [1024] ||e||^2 + C_SHIFT (legacy order)
// per-row partials, NSPLIT splits each
#define PART_STRIDE (NSPLIT * N_ROWS)     // 131072
#define WS_PART_S  8192
#define WS_PART_U  (8192 + PART_STRIDE)
#define WS_PART_AB (8192 + 2 * PART_STRIDE)   // packed i1*1024+i2 (as float)
#define WS_EB      (8192 + 3 * PART_STRIDE)
// fp16x2 E records: 64 chunks x (4 frags x 64 lanes x 16B + 16 f32 e2l)
#define CHUNK_F4  260                     // float4s per chunk record
#define MAIN_CHUNKS 16                    // 16-code chunks per K-split
#define MEMSET_BYTES (6144 * 4)           // hist + accs + gram

// ---- out float-index layout (reference return order, concatenated) ----
#define OUT_Q      0
#define OUT_COMMIT 2097152
#define OUT_ORTHO  2097153
#define OUT_ENT    2097154
#define OUT_PERP   2097155
#define OUT_COV    2097156
#define OUT_IDX    2097157

typedef __attribute__((ext_vector_type(8))) _Float16 f16x8;  // 8 f16 = 4 VGPR
typedef __attribute__((ext_vector_type(4))) float f32x4;

// Bit-identical replica of the legacy fp32 logit chain (for candidate rescue)
__device__ inline float exact_g(const float4* X, const float* __restrict__ emb,
                                int k, float e2ck) {
    const float4* e4 = (const float4*)(emb + (size_t)k * D_DIM);
    float d0 = 0.f, d1 = 0.f, d2 = 0.f, d3 = 0.f;
#pragma unroll
    for (int j = 0; j < 16; j += 4) {
        float4 ea = e4[j], eb = e4[j + 1], ec = e4[j + 2], ed = e4[j + 3];
        float4 xa = X[j], xb = X[j + 1], xc = X[j + 2], xd = X[j + 3];
        d0 = fmaf(ea.x, xa.x, d0); d0 = fmaf(ea.y, xa.y, d0);
        d0 = fmaf(ea.z, xa.z, d0); d0 = fmaf(ea.w, xa.w, d0);
        d1 = fmaf(eb.x, xb.x, d1); d1 = fmaf(eb.y, xb.y, d1);
        d1 = fmaf(eb.z, xb.z, d1); d1 = fmaf(eb.w, xb.w, d1);
        d2 = fmaf(ec.x, xc.x, d2); d2 = fmaf(ec.y, xc.y, d2);
        d2 = fmaf(ec.z, xc.z, d2); d2 = fmaf(ec.w, xc.w, d2);
        d3 = fmaf(ed.x, xd.x, d3); d3 = fmaf(ed.y, xd.y, d3);
        d3 = fmaf(ed.z, xd.z, d3); d3 = fmaf(ed.w, xd.w, d3);
    }
    return fmaf(2.0f, (d0 + d1) + (d2 + d3), -e2ck);
}

// fp16x2 decomposition of 8 floats -> (hi, mid) f16x8 pair.
__device__ inline void decomp2x8(const float* v, f16x8& h, f16x8& m) {
#pragma unroll
    for (int i = 0; i < 8; ++i) {
        _Float16 hh = (_Float16)v[i];
        h[i] = hh;
        m[i] = (_Float16)(v[i] - (float)hh);
    }
}

// Fused prep (blocks 0..15) + ortho gram partials (blocks 16..31).
// Both depend only on emb/cc and write disjoint ws regions.
__global__ __launch_bounds__(256) void vq_prep_ortho(const float* __restrict__ emb,
                                                     const float* __restrict__ cc,
                                                     float* __restrict__ ws) {
    __shared__ float srows[64][64];
    __shared__ float rn2[64];
    const int t = threadIdx.x;

    if (blockIdx.x < 16) {
        // ---- prep: E-fragment fp16x2 decomposition + ||e||^2 (+ nused)
        const int tid  = blockIdx.x * 256 + t;            // 0..4095
        const int c    = tid >> 6;
        const int lane = tid & 63;
        const int col  = lane & 15;
        const int kg   = lane >> 4;
        const int code = c * 16 + col;
        float4* EB4 = (float4*)(ws + WS_EB);
#pragma unroll
        for (int s = 0; s < 2; ++s) {
            const float* ep = emb + (size_t)code * D_DIM + s * 32 + kg * 8;
            float4 A4 = *(const float4*)ep;
            float4 B4 = *(const float4*)(ep + 4);
            float v[8] = {A4.x, A4.y, A4.z, A4.w, B4.x, B4.y, B4.z, B4.w};
            union { f16x8 h; float4 f; } th, tm;
            decomp2x8(v, th.h, tm.h);
            const int base = c * CHUNK_F4;
            EB4[base + (s * 2 + 0) * 64 + lane] = th.f;   // hi  frag, k-step s
            EB4[base + (s * 2 + 1) * 64 + lane] = tm.f;   // mid frag, k-step s
        }
        if (kg == 0) {
            // legacy sequential order -> ws[WS_E2C] bitwise matches prior rounds
            const float4* e4 = (const float4*)(emb + (size_t)code * D_DIM);
            float ssum = 0.f;
#pragma unroll
            for (int j = 0; j < 16; ++j) {
                float4 v = e4[j];
                ssum += v.x * v.x + v.y * v.y + v.z * v.z + v.w * v.w;
            }
            float e2c = ssum + C_SHIFT;
            ws[WS_E2C + code] = e2c;
            ((float*)(EB4 + c * CHUNK_F4 + 256))[col] = e2c * LOG2E_F;  // base-2
            if (cc[code] >= 1.0f) atomicAdd(&ws[WS_NUSED], 1.0f);
        }
        return;
    }

    // ---- ortho: block b owns codes [64b, 64b+64); partial 64x64 gram
    const int k0 = (blockIdx.x - 16) * 64;
    const int rb = t >> 4;            // 0..15
    const int c4 = (t & 15) << 2;     // float4 col

#pragma unroll
    for (int i = 0; i < 4; ++i) {
        const int r = i * 16 + rb;
        float4 v = *(const float4*)(emb + (size_t)(k0 + r) * D_DIM + c4);
        *(float4*)(&srows[r][c4]) = v;
        float ss = v.x * v.x + v.y * v.y + v.z * v.z + v.w * v.w;
        ss += __shfl_down(ss, 8, 16);
        ss += __shfl_down(ss, 4, 16);
        ss += __shfl_down(ss, 2, 16);
        ss += __shfl_down(ss, 1, 16);
        if ((t & 15) == 0) {
            float nrm = fmaxf(sqrtf(ss), 1e-12f);
            float m = (cc[k0 + r] >= 1.0f) ? 1.0f : 0.0f;
            rn2[r] = m / (nrm * nrm);     // rnorm^2, folded into A side
        }
    }
    __syncthreads();

    const int a  = t >> 2;
    const int b0 = (t & 3) << 4;
    float acc[16];
#pragma unroll
    for (int i = 0; i < 16; ++i) acc[i] = 0.f;

#pragma unroll 4
    for (int k = 0; k < 64; ++k) {
        float na = srows[k][a] * rn2[k];
        const float* rbp = &srows[k][b0];
#pragma unroll
        for (int i = 0; i < 16; ++i) acc[i] = fmaf(na, rbp[i], acc[i]);
    }
#pragma unroll
    for (int i = 0; i < 16; ++i)
        atomicAdd(&ws[WS_G + a * 64 + b0 + i], acc[i]);
}

#define MFMA_F16 __builtin_amdgcn_mfma_f32_16x16x32_f16

// 1024 blocks x 256 thr. Block = (row-group of 128, K-split of 256 codes).
// Wave = 32 rows (2 tiles of 16) x 256 codes; fp16x2 4-term MFMA emulation.
// Round-5 counters: VGPR=64 (64 arch/64 acc split at the (4,4) 128-reg tier,
// epilogue state shuttles via AGPR) AND Occupancy 18% (512 blocks = only
// 2 waves/SIMD). This round doubles TLP: 1024 blocks -> 4 waves/SIMD (the
// (4,4) cap) so stalls + shuttle overlap across waves. B-frag L2 traffic
// unchanged (2x waves x 1/2 chunks each).
__global__ __launch_bounds__(256)
__attribute__((amdgpu_waves_per_eu(4, 4)))
void vq_main(const float* __restrict__ inp, float* __restrict__ ws) {
    const int t    = threadIdx.x;
    const int lane = t & 63;
    const int wave = t >> 6;
    const int col  = lane & 15;
    const int kg   = lane >> 4;
    const int rg   = blockIdx.x >> 2;      // row group 0..255 (128 rows)
    const int sp   = blockIdx.x & 3;       // k split 0..3 (256 codes)
    const int wbase = rg * 128 + wave * 32;

    // A-frags: xa[tile][0]=h k0, [1]=m k0, [2]=h k1, [3]=m k1
    f16x8 xa[2][4];
#pragma unroll
    for (int tt = 0; tt < 2; ++tt) {
        const float* xp = inp + (size_t)(wbase + tt * 16 + col) * D_DIM + kg * 8;
#pragma unroll
        for (int s = 0; s < 2; ++s) {
            float4 A4 = *(const float4*)(xp + s * 32);
            float4 B4 = *(const float4*)(xp + s * 32 + 4);
            float v[8] = {A4.x, A4.y, A4.z, A4.w, B4.x, B4.y, B4.z, B4.w};
            decomp2x8(v, xa[tt][s * 2 + 0], xa[tt][s * 2 + 1]);
        }
    }

    const float4* EBp = (const float4*)(ws + WS_EB)
                      + (size_t)sp * MAIN_CHUNKS * CHUNK_F4;

    float sa[2][4], ua[2][4], m1[2][4], m2[2][4];
    int i12[2][4];
#pragma unroll
    for (int tt = 0; tt < 2; ++tt)
#pragma unroll
        for (int q = 0; q < 4; ++q) {
            sa[tt][q] = 0.f; ua[tt][q] = 0.f;
            m1[tt][q] = -1e30f; m2[tt][q] = -1e30f;
            i12[tt][q] = 0;
        }

#pragma unroll 2
    for (int c = 0; c < MAIN_CHUNKS; ++c) {
        const float4* p = EBp + (size_t)c * CHUNK_F4;
        const f16x8* pb = (const f16x8*)p;
        f16x8 bh0 = pb[0 * 64 + lane];     // hi,  k-step 0
        f16x8 bm0 = pb[1 * 64 + lane];     // mid, k-step 0
        f16x8 bh1 = pb[2 * 64 + lane];     // hi,  k-step 1
        f16x8 bm1 = pb[3 * 64 + lane];     // mid, k-step 1
        const float e2v = ((const float*)(p + 256))[col];

        f32x4 acc[2];
#pragma unroll
        for (int tt = 0; tt < 2; ++tt) acc[tt] = (f32x4){0.f, 0.f, 0.f, 0.f};

        // 4-term fp16x2 per k-step; tile-interleave keeps 2 chains independent
#pragma unroll
        for (int tt = 0; tt < 2; ++tt) acc[tt] = MFMA_F16(xa[tt][0], bh0, acc[tt], 0, 0, 0);
#pragma unroll
        for (int tt = 0; tt < 2; ++tt) acc[tt] = MFMA_F16(xa[tt][2], bh1, acc[tt], 0, 0, 0);
#pragma unroll
        for (int tt = 0; tt < 2; ++tt) acc[tt] = MFMA_F16(xa[tt][1], bh0, acc[tt], 0, 0, 0);
#pragma unroll
        for (int tt = 0; tt < 2; ++tt) acc[tt] = MFMA_F16(xa[tt][3], bh1, acc[tt], 0, 0, 0);
#pragma unroll
        for (int tt = 0; tt < 2; ++tt) acc[tt] = MFMA_F16(xa[tt][0], bm0, acc[tt], 0, 0, 0);
#pragma unroll
        for (int tt = 0; tt < 2; ++tt) acc[tt] = MFMA_F16(xa[tt][2], bm1, acc[tt], 0, 0, 0);
#pragma unroll
        for (int tt = 0; tt < 2; ++tt) acc[tt] = MFMA_F16(xa[tt][1], bm0, acc[tt], 0, 0, 0);
#pragma unroll
        for (int tt = 0; tt < 2; ++tt) acc[tt] = MFMA_F16(xa[tt][3], bm1, acc[tt], 0, 0, 0);

        const int cb = sp * 256 + c * 16 + col;        // global code index
#pragma unroll
        for (int tt = 0; tt < 2; ++tt)
#pragma unroll
            for (int q = 0; q < 4; ++q) {
                // base-2 shifted logit: g = 2*log2e*dot - log2e*(e2+C_SHIFT)
                float g = fmaf(2.0f * LOG2E_F, acc[tt][q], -e2v);
                float pw;
                asm("v_exp_f32 %0, %1" : "=v"(pw) : "v"(g));   // 2^g
                sa[tt][q] += pw;
                ua[tt][q] = fmaf(pw, g, ua[tt][q]);
                bool gt1 = g > m1[tt][q];
                bool gt2 = g > m2[tt][q];
                int t1 = (cb << 10) | (i12[tt][q] >> 10);      // new i1=cb, i2=old i1
                int t2 = (i12[tt][q] & ~1023) | cb;            // new i2=cb
                i12[tt][q] = gt1 ? t1 : (gt2 ? t2 : i12[tt][q]);
                m2[tt][q] = __builtin_amdgcn_fmed3f(g, m2[tt][q], m1[tt][q]);
                m1[tt][q] = fmaxf(m1[tt][q], g);
            }
    }

    // per-row reduce across the 16 lanes sharing each C-row
#pragma unroll
    for (int off = 1; off < 16; off <<= 1) {
#pragma unroll
        for (int tt = 0; tt < 2; ++tt)
#pragma unroll
            for (int q = 0; q < 4; ++q) {
                sa[tt][q] += __shfl_xor(sa[tt][q], off);
                ua[tt][q] += __shfl_xor(ua[tt][q], off);
                float bm1v = __shfl_xor(m1[tt][q], off);
                float bm2v = __shfl_xor(m2[tt][q], off);
                int   biv  = __shfl_xor(i12[tt][q], off);
                if (bm1v > m1[tt][q]) {
                    if (bm2v > m1[tt][q]) {        // both from partner
                        m2[tt][q] = bm2v; i12[tt][q] = biv;
                    } else {                        // partner's 1st, our 1st
                        m2[tt][q] = m1[tt][q];
                        i12[tt][q] = (biv & ~1023 & 0xFFFFFC00) | (i12[tt][q] >> 10);
                        i12[tt][q] = ((biv >> 10) << 10) | (i12[tt][q] & 1023);
                    }
                    m1[tt][q] = bm1v;
                } else if (bm1v > m2[tt][q]) {      // partner's 1st is our 2nd
                    m2[tt][q] = bm1v;
                    i12[tt][q] = (i12[tt][q] & ~1023) | (biv >> 10);
                }
            }
    }

    if (col == 0) {
#pragma unroll
        for (int tt = 0; tt < 2; ++tt)
#pragma unroll
            for (int q = 0; q < 4; ++q) {
                const int r  = wbase + tt * 16 + kg * 4 + q;
                const int pi = sp * N_ROWS + r;
                ws[WS_PART_S + pi]  = sa[tt][q];
                ws[WS_PART_U + pi]  = ua[tt][q];
                ws[WS_PART_AB + pi] = (float)i12[tt][q];
            }
    }
}

// 512 blocks x 64 thr; thread = row. Merge 4 splits, exact fp32 rescue of the
// <=8 approx candidates (legacy argmin semantics), epilogue.
__global__ __launch_bounds__(64) void vq_combine(const float* __restrict__ inp,
                                                 const float* __restrict__ emb,
                                                 float* __restrict__ ws,
                                                 float* __restrict__ out) {
    const int lane = threadIdx.x;
    const int row  = blockIdx.x * 64 + lane;

    float S = 0.f, U2 = 0.f;
    int cand[8];
#pragma unroll
    for (int sp = 0; sp < NSPLIT; ++sp) {
        const int pi = sp * N_ROWS + row;
        S  += ws[WS_PART_S + pi];
        U2 += ws[WS_PART_U + pi];
        int ab = (int)ws[WS_PART_AB + pi];
        cand[2 * sp]     = ab >> 10;
        cand[2 * sp + 1] = ab & 1023;
    }
    float U = U2 * LN2_F;                             // base-2 -> nats

    float4 X[16];
    const float4* xr = (const float4*)(inp + (size_t)row * D_DIM);
#pragma unroll
    for (int j = 0; j < 16; ++j) X[j] = xr[j];

    float bestg = -1e30f; int I = K_CODES;
#pragma unroll 2
    for (int j = 0; j < 8; ++j) {
        const int c = cand[j];
        float g = exact_g(X, emb, c, ws[WS_E2C + c]);
        if (g > bestg || (g == bestg && c < I)) { bestg = g; I = c; }
    }

    float H = logf(S) - U / S;                        // per-row entropy (nats)

    out[OUT_IDX + row] = (float)I;
    atomicAdd(&ws[WS_HIST + I], 1.0f);

    const float4* q4 = (const float4*)(emb + (size_t)I * D_DIM);
    float4* oq = (float4*)out + (size_t)row * 16;
    float cs = 0.f;
#pragma unroll
    for (int j = 0; j < 16; ++j) {
        float4 q = q4[j], x = X[j];
        float dx = q.x - x.x, dy = q.y - x.y, dz = q.z - x.z, dw = q.w - x.w;
        cs += dx * dx + dy * dy + dz * dz + dw * dw;
        float4 o;
        o.x = x.x + dx; o.y = x.y + dy; o.z = x.z + dz; o.w = x.w + dw;
        oq[j] = o;
    }
#pragma unroll
    for (int off = 32; off; off >>= 1) {
        H  += __shfl_down(H, off);
        cs += __shfl_down(cs, off);
    }
    if (lane == 0) {
        atomicAdd(&ws[WS_ACC_H], H);
        atomicAdd(&ws[WS_ACC_C], cs);
    }
}

__global__ __launch_bounds__(256) void vq_finalize(const float* __restrict__ ws,
                                                   float* __restrict__ out) {
    __shared__ float redP[4], redG[4];
    const int t = threadIdx.x;
    float hp = 0.f, gg = 0.f;
    for (int k = t; k < K_CODES; k += 256) {
        float p = ws[WS_HIST + k] * (1.0f / (float)N_ROWS);
        hp += p * logf(p + 1e-10f);
    }
    for (int i = t; i < 4096; i += 256) {
        float g = ws[WS_G + i];
        gg = fmaf(g, g, gg);
    }
#pragma unroll
    for (int off = 32; off; off >>= 1) {
        hp += __shfl_down(hp, off);
        gg += __shfl_down(gg, off);
    }
    if ((t & 63) == 0) { redP[t >> 6] = hp; redG[t >> 6] = gg; }
    __syncthreads();
    if (t == 0) {
        float hsum = redP[0] + redP[1] + redP[2] + redP[3];
        float gsum = redG[0] + redG[1] + redG[2] + redG[3];
        float nu = ws[WS_NUSED];
        out[OUT_PERP]   = expf(-hsum);
        out[OUT_ENT]    = ws[WS_ACC_H] * (1.0f / (float)N_ROWS) * 0.1f; // /log2(1024)
        out[OUT_COMMIT] = ws[WS_ACC_C] * (1.0f / ((float)N_ROWS * (float)D_DIM));
        out[OUT_ORTHO]  = gsum / (nu * nu) - 1.0f / nu;
        out[OUT_COV]    = nu * (1.0f / (float)K_CODES);
    }
}

extern "C" void kernel_launch(void* const* d_in, const int* in_sizes, int n_in,
                              void* d_out, int out_size, void* d_ws, size_t ws_size,
                              hipStream_t stream) {
    const float* inp = (const float*)d_in[0];   // [16,2048,64]
    const float* emb = (const float*)d_in[1];   // [1024,64]
    const float* cc  = (const float*)d_in[2];   // [1024]
    float* out = (float*)d_out;
    float* ws  = (float*)d_ws;

    hipMemsetAsync(d_ws, 0, MEMSET_BYTES, stream);
    vq_prep_ortho<<<32, 256, 0, stream>>>(emb, cc, ws);
    vq_main<<<(N_ROWS / 128) * NSPLIT, 256, 0, stream>>>(inp, ws);
    vq_combine<<<N_ROWS / 64, 64, 0, stream>>>(inp, emb, ws, out);
    vq_finalize<<<1, 256, 0, stream>>>(ws, out);
}